// Round 4
// baseline (616.442 us; speedup 1.0000x reference)
//
#include <hip/hip_runtime.h>
#include <hip/hip_bf16.h>

// VAE_RNN: B=4096, T=200, D=128, L=64, H=128, CIN=2L+D=256
// Persistent-block RNN, 256 blocks x 256 threads (4 FAT waves), 16 rows/block.
// Rationale: LDS pipe is per-CU and every wave must read full operand tiles,
// so traffic scales with waves/CU. 4 waves (1/SIMD, ~330 VGPRs each, weights
// register-resident) halve LDS instruction traffic vs the 8-wave variant.
// mfma(W_frag, act_frag, acc) => lane holds 4 consecutive features of one
// batch row; biases are folded into accumulator INIT. Linear LDS layout
// (row stride 528B/272B: 132/68 dwords = 4 mod 32 -> inherent-2-way only),
// single base pointer per phase + immediate ds_read offsets.
// Barriers are lgkmcnt-only: the x(t+1) global prefetch stays in flight.

#define NB 4096
#define NT 200
#define ND 128

typedef __bf16 bf16;
typedef __attribute__((ext_vector_type(8))) __bf16 bf16x8;
typedef __attribute__((ext_vector_type(4))) __bf16 bf16x4;
typedef __attribute__((ext_vector_type(4))) float f32x4;

#define BAR() asm volatile("s_waitcnt lgkmcnt(0)\n\ts_barrier" ::: "memory")

__device__ __forceinline__ f32x4 mfma16(bf16x8 a, bf16x8 b, f32x4 c){
    return __builtin_amdgcn_mfma_f32_16x16x32_bf16(a, b, c, 0, 0, 0);
}
// inf-safe, branch-free
__device__ __forceinline__ float fast_tanh(float x){
    float e = __expf(2.f * x);
    return 1.f - 2.f * __builtin_amdgcn_rcpf(e + 1.f);
}
__device__ __forceinline__ float fast_sigmoid(float x){
    return __builtin_amdgcn_rcpf(1.f + __expf(-x));
}
__device__ __forceinline__ bf16x4 tanh4(f32x4 a){
    bf16x4 o;
    o[0] = (bf16)fast_tanh(a[0]);
    o[1] = (bf16)fast_tanh(a[1]);
    o[2] = (bf16)fast_tanh(a[2]);
    o[3] = (bf16)fast_tanh(a[3]);
    return o;
}
__device__ __forceinline__ f32x4 finit(float4 b){
    f32x4 r; r[0]=b.x; r[1]=b.y; r[2]=b.z; r[3]=b.w; return r;
}

__global__ __launch_bounds__(256, 1)
void vae_rnn(const float* __restrict__ data,
             const float* __restrict__ ug_w1, const float* __restrict__ ug_b1,
             const float* __restrict__ ug_w2, const float* __restrict__ ug_b2,
             const float* __restrict__ rg_w1, const float* __restrict__ rg_b1,
             const float* __restrict__ rg_w2, const float* __restrict__ rg_b2,
             const float* __restrict__ ns_w1, const float* __restrict__ ns_b1,
             const float* __restrict__ ns_w2, const float* __restrict__ ns_b2,
             float* __restrict__ out)
{
    __shared__ __align__(16) char h_lds [16 * 528];   // 16 x 256 bf16 rows (+pad)
    __shared__ __align__(16) char t_lds [16 * 528];   // tanh(l1) of [ug|rg]
    __shared__ __align__(16) char tn_lds[16 * 272];   // tanh(l1) of ns
    __shared__ float u_lds [16][68];                  // u gate fp32
    __shared__ float ys_lds[16][132];                 // y (0..63), s (64..127) fp32

    const int tid  = threadIdx.x;
    const int w    = tid >> 6;          // wave 0..3
    const int lane = tid & 63;
    const int lq   = lane >> 4;         // quarter 0..3
    const int lc   = lane & 15;         // batch row within tile
    const int row0 = blockIdx.x * 16;
    const bool RU  = (w < 2);           // B-role: u-gate (else r-gate)
    const int  w2  = RU ? w : (w - 2);  // role-local wave index

    // ================= persistent weight fragments (registers) ==============
    // A: h(16x256) @ [ug_w1|rg_w1](256x256); wave w owns feats [64w,64w+64)
    bf16x8 wA[32]; float4 bA[4];
    {
        const float* W  = RU ? ug_w1 : rg_w1;    // feats<128 <=> w<2
        const float* bb = RU ? ug_b1 : rg_b1;
        #pragma unroll
        for (int j = 0; j < 4; ++j){
            int n  = (w*64 + j*16 + lc) & 127;
            int fb = (w*64 + j*16 + lq*4) & 127;
            bA[j] = make_float4(bb[fb], bb[fb+1], bb[fb+2], bb[fb+3]);
            #pragma unroll
            for (int kt = 0; kt < 8; ++kt){
                bf16x8 f;
                #pragma unroll
                for (int e = 0; e < 8; ++e) f[e] = (bf16)W[(kt*32 + lq*8 + e)*128 + n];
                wA[kt*4 + j] = f;
            }
        }
    }
    // B: t_half(16x128) @ w2(128x64); waves 0,1: u cols; waves 2,3: r cols
    bf16x8 wB[8]; float4 bB[2];
    {
        const float* W  = RU ? ug_w2 : rg_w2;
        const float* bb = RU ? ug_b2 : rg_b2;
        #pragma unroll
        for (int j = 0; j < 2; ++j){
            int n  = w2*32 + j*16 + lc;
            int fb = w2*32 + j*16 + lq*4;
            bB[j] = make_float4(bb[fb], bb[fb+1], bb[fb+2], bb[fb+3]);
            #pragma unroll
            for (int kt = 0; kt < 4; ++kt){
                bf16x8 f;
                #pragma unroll
                for (int e = 0; e < 8; ++e) f[e] = (bf16)W[(kt*32 + lq*8 + e)*64 + n];
                wB[kt*2 + j] = f;
            }
        }
    }
    // C: hc(16x256) @ ns_w1(256x128); wave w owns feats [32w,32w+32)
    bf16x8 wC[16]; float4 bC[2];
    {
        #pragma unroll
        for (int j = 0; j < 2; ++j){
            int n  = w*32 + j*16 + lc;
            int fb = w*32 + j*16 + lq*4;
            bC[j] = make_float4(ns_b1[fb], ns_b1[fb+1], ns_b1[fb+2], ns_b1[fb+3]);
            #pragma unroll
            for (int kt = 0; kt < 8; ++kt){
                bf16x8 f;
                #pragma unroll
                for (int e = 0; e < 8; ++e) f[e] = (bf16)ns_w1[(kt*32 + lq*8 + e)*128 + n];
                wC[kt*2 + j] = f;
            }
        }
    }
    // D: tn(16x128) @ ns_w2(128x128); waves 0,1: mean cols, waves 2,3: std cols
    const int nb0 = RU ? (w*32) : (64 + w2*32);
    bf16x8 wD[8]; float4 bD[2];
    {
        #pragma unroll
        for (int j = 0; j < 2; ++j){
            int n  = nb0 + j*16 + lc;
            int fb = nb0 + j*16 + lq*4;
            bD[j] = make_float4(ns_b2[fb], ns_b2[fb+1], ns_b2[fb+2], ns_b2[fb+3]);
            #pragma unroll
            for (int kt = 0; kt < 4; ++kt){
                bf16x8 f;
                #pragma unroll
                for (int e = 0; e < 8; ++e) f[e] = (bf16)ns_w2[(kt*32 + lq*8 + e)*128 + n];
                wD[kt*2 + j] = f;
            }
        }
    }

    // ================= LDS bases (loop-invariant) ============================
    const char* h_rd  = h_lds  + lc*528 + lq*16;            // + kt*64
    char*       t_wr  = t_lds  + lc*528 + w*128 + lq*8;     // + 32*j
    const char* t_rd  = t_lds  + lc*528 + lq*16 + (RU ? 0 : 256);
    char*       tn_wr = tn_lds + lc*272 + w*64 + lq*8;      // + 32*j
    const char* tn_rd = tn_lds + lc*272 + lq*16;            // + kt*64

    // ================= init: ys=0, h=[0|0|x(0)] ==============================
    for (int i = tid; i < 16*132; i += 256) (&ys_lds[0][0])[i] = 0.f;
    const int xr  = tid >> 4;            // 0..15
    const int xci = tid & 15;            // 16B chunk index
    const float* xbase = data + (size_t)(row0 + xr) * (NT * ND) + xci*8;
    {
        bf16x8 z = {};
        *(bf16x8*)(h_lds + xr*528 + xci*16) = z;           // y,s cols = 0
        float4 a0 = *(const float4*)(xbase);
        float4 a1 = *(const float4*)(xbase + 4);
        bf16x8 xb = { (bf16)a0.x,(bf16)a0.y,(bf16)a0.z,(bf16)a0.w,
                      (bf16)a1.x,(bf16)a1.y,(bf16)a1.z,(bf16)a1.w };
        *(bf16x8*)(h_lds + xr*528 + 256 + xci*16) = xb;    // x cols
    }
    BAR();

    const int cB = w2*32 + lq*4;        // B-phase r/u column base
    const int cD = nb0 + lq*4;          // D-phase ys column base
    const int uD = (nb0 & 63) + lq*4;   // D-phase u column base

    #pragma unroll 1
    for (int t = 0; t < NT; ++t){
        // x(t+1) prefetch: in flight across all lgkm-only barriers, used in D
        int tn1 = (t + 1 < NT) ? (t + 1) : (NT - 1);
        float4 xn0 = *(const float4*)(xbase + tn1*ND);
        float4 xn1 = *(const float4*)(xbase + tn1*ND + 4);

        // ---- Phase A: t = tanh(h @ W1 + b1)  (32 MFMA, 4 chains) ----
        bf16x8 xf0, xf1, xf2, xf3;
        f32x4 a0 = finit(bA[0]), a1 = finit(bA[1]), a2 = finit(bA[2]), a3 = finit(bA[3]);
        #pragma unroll
        for (int kt = 0; kt < 8; ++kt){
            bf16x8 av = *(const bf16x8*)(h_rd + kt*64);
            if (kt == 4) xf0 = av;
            if (kt == 5) xf1 = av;
            if (kt == 6) xf2 = av;
            if (kt == 7) xf3 = av;
            a0 = mfma16(wA[kt*4+0], av, a0);
            a1 = mfma16(wA[kt*4+1], av, a1);
            a2 = mfma16(wA[kt*4+2], av, a2);
            a3 = mfma16(wA[kt*4+3], av, a3);
        }
        *(bf16x4*)(t_wr +  0) = tanh4(a0);
        *(bf16x4*)(t_wr + 32) = tanh4(a1);
        *(bf16x4*)(t_wr + 64) = tanh4(a2);
        *(bf16x4*)(t_wr + 96) = tanh4(a3);
        BAR();

        // ---- Phase B: u|r = sigmoid(t_half @ W2 + b2); + C's x-part MFMAs ----
        float4 y4a, s4a, y4b, s4b;
        if (!RU){
            y4a = *(const float4*)&ys_lds[lc][cB];
            s4a = *(const float4*)&ys_lds[lc][64 + cB];
            y4b = *(const float4*)&ys_lds[lc][cB + 16];
            s4b = *(const float4*)&ys_lds[lc][80 + cB];
        }
        f32x4 b0 = finit(bB[0]), b1 = finit(bB[1]);
        f32x4 cx0 = finit(bC[0]), cx1 = finit(bC[1]);   // C acc, x-part (carried)
        #pragma unroll
        for (int kt = 0; kt < 4; ++kt){
            bf16x8 tv = *(const bf16x8*)(t_rd + kt*64);
            b0 = mfma16(wB[kt*2+0], tv, b0);
            b1 = mfma16(wB[kt*2+1], tv, b1);
        }
        cx0 = mfma16(wC[ 8], xf0, cx0);  cx1 = mfma16(wC[ 9], xf0, cx1);
        cx0 = mfma16(wC[10], xf1, cx0);  cx1 = mfma16(wC[11], xf1, cx1);
        cx0 = mfma16(wC[12], xf2, cx0);  cx1 = mfma16(wC[13], xf2, cx1);
        cx0 = mfma16(wC[14], xf3, cx0);  cx1 = mfma16(wC[15], xf3, cx1);
        {
            float g00 = fast_sigmoid(b0[0]), g01 = fast_sigmoid(b0[1]);
            float g02 = fast_sigmoid(b0[2]), g03 = fast_sigmoid(b0[3]);
            float g10 = fast_sigmoid(b1[0]), g11 = fast_sigmoid(b1[1]);
            float g12 = fast_sigmoid(b1[2]), g13 = fast_sigmoid(b1[3]);
            if (RU){
                *(float4*)&u_lds[lc][cB]      = make_float4(g00, g01, g02, g03);
                *(float4*)&u_lds[lc][cB + 16] = make_float4(g10, g11, g12, g13);
            } else {
                bf16x4 hy0 = { (bf16)(y4a.x*g00), (bf16)(y4a.y*g01), (bf16)(y4a.z*g02), (bf16)(y4a.w*g03) };
                bf16x4 hs0 = { (bf16)(s4a.x*g00), (bf16)(s4a.y*g01), (bf16)(s4a.z*g02), (bf16)(s4a.w*g03) };
                bf16x4 hy1 = { (bf16)(y4b.x*g10), (bf16)(y4b.y*g11), (bf16)(y4b.z*g12), (bf16)(y4b.w*g13) };
                bf16x4 hs1 = { (bf16)(s4b.x*g10), (bf16)(s4b.y*g11), (bf16)(s4b.z*g12), (bf16)(s4b.w*g13) };
                char* hw = h_lds + lc*528 + 2*cB;
                *(bf16x4*)(hw +   0) = hy0;           // y*r cols
                *(bf16x4*)(hw +  32) = hy1;
                *(bf16x4*)(hw + 128) = hs0;           // s*r cols (+64 feats)
                *(bf16x4*)(hw + 160) = hs1;
            }
        }
        BAR();

        // ---- Phase C: tn = tanh(hc @ ns_w1 + b)  (hc-part only; x-part done) ----
        #pragma unroll
        for (int kt = 0; kt < 4; ++kt){
            bf16x8 hv = *(const bf16x8*)(h_rd + kt*64);
            cx0 = mfma16(wC[kt*2+0], hv, cx0);
            cx1 = mfma16(wC[kt*2+1], hv, cx1);
        }
        *(bf16x4*)(tn_wr +  0) = tanh4(cx0);
        *(bf16x4*)(tn_wr + 32) = tanh4(cx1);
        BAR();

        // ---- Phase D: ns = tn @ ns_w2 + b; EMA; refresh h state + x(t+1) ----
        {
            float4 u4a = *(const float4*)&u_lds[lc][uD];
            float4 u4b = *(const float4*)&u_lds[lc][uD + 16];
            float4 o4a = *(const float4*)&ys_lds[lc][cD];
            float4 o4b = *(const float4*)&ys_lds[lc][cD + 16];
            f32x4 d0 = finit(bD[0]), d1 = finit(bD[1]);
            #pragma unroll
            for (int kt = 0; kt < 4; ++kt){
                bf16x8 tv = *(const bf16x8*)(tn_rd + kt*64);
                d0 = mfma16(wD[kt*2+0], tv, d0);
                d1 = mfma16(wD[kt*2+1], tv, d1);
            }
            float v00 = d0[0], v01 = d0[1], v02 = d0[2], v03 = d0[3];
            float v10 = d1[0], v11 = d1[1], v12 = d1[2], v13 = d1[3];
            if (!RU){
                v00 = fabsf(v00); v01 = fabsf(v01); v02 = fabsf(v02); v03 = fabsf(v03);
                v10 = fabsf(v10); v11 = fabsf(v11); v12 = fabsf(v12); v13 = fabsf(v13);
            }
            float n00 = fmaf(u4a.x, o4a.x - v00, v00);
            float n01 = fmaf(u4a.y, o4a.y - v01, v01);
            float n02 = fmaf(u4a.z, o4a.z - v02, v02);
            float n03 = fmaf(u4a.w, o4a.w - v03, v03);
            float n10 = fmaf(u4b.x, o4b.x - v10, v10);
            float n11 = fmaf(u4b.y, o4b.y - v11, v11);
            float n12 = fmaf(u4b.z, o4b.z - v12, v12);
            float n13 = fmaf(u4b.w, o4b.w - v13, v13);
            *(float4*)&ys_lds[lc][cD]      = make_float4(n00, n01, n02, n03);
            *(float4*)&ys_lds[lc][cD + 16] = make_float4(n10, n11, n12, n13);
            bf16x4 h0 = { (bf16)n00, (bf16)n01, (bf16)n02, (bf16)n03 };
            bf16x4 h1 = { (bf16)n10, (bf16)n11, (bf16)n12, (bf16)n13 };
            char* hw = h_lds + lc*528 + 2*cD;
            *(bf16x4*)(hw +  0) = h0;
            *(bf16x4*)(hw + 32) = h1;
            // refresh x cols with x(t+1) (vmcnt waited here, issued a step ago)
            bf16x8 xb = { (bf16)xn0.x,(bf16)xn0.y,(bf16)xn0.z,(bf16)xn0.w,
                          (bf16)xn1.x,(bf16)xn1.y,(bf16)xn1.z,(bf16)xn1.w };
            *(bf16x8*)(h_lds + xr*528 + 256 + xci*16) = xb;
        }
        BAR();
    }

    // output: yT (4096x64) then sT (4096x64), fp32
    {
        int xc8 = xci * 8;
        float4 v0 = *(const float4*)&ys_lds[xr][xc8];
        float4 v1 = *(const float4*)&ys_lds[xr][xc8 + 4];
        size_t gr = (size_t)(row0 + xr);
        if (xc8 < 64){
            *(float4*)&out[gr*64 + xc8]     = v0;
            *(float4*)&out[gr*64 + xc8 + 4] = v1;
        } else {
            *(float4*)&out[(size_t)NB*64 + gr*64 + (xc8 - 64)]     = v0;
            *(float4*)&out[(size_t)NB*64 + gr*64 + (xc8 - 64) + 4] = v1;
        }
    }
}

extern "C" void kernel_launch(void* const* d_in, const int* in_sizes, int n_in,
                              void* d_out, int out_size, void* d_ws, size_t ws_size,
                              hipStream_t stream) {
    const float* data  = (const float*)d_in[0];
    // d_in[1] = time_steps — unused by the reference computation
    const float* ug_w1 = (const float*)d_in[2];
    const float* ug_b1 = (const float*)d_in[3];
    const float* ug_w2 = (const float*)d_in[4];
    const float* ug_b2 = (const float*)d_in[5];
    const float* rg_w1 = (const float*)d_in[6];
    const float* rg_b1 = (const float*)d_in[7];
    const float* rg_w2 = (const float*)d_in[8];
    const float* rg_b2 = (const float*)d_in[9];
    const float* ns_w1 = (const float*)d_in[10];
    const float* ns_b1 = (const float*)d_in[11];
    const float* ns_w2 = (const float*)d_in[12];
    const float* ns_b2 = (const float*)d_in[13];

    hipLaunchKernelGGL(vae_rnn, dim3(NB/16), dim3(256), 0, stream,
                       data, ug_w1, ug_b1, ug_w2, ug_b2,
                       rg_w1, rg_b1, rg_w2, rg_b2,
                       ns_w1, ns_b1, ns_w2, ns_b2,
                       (float*)d_out);
}